// Round 7
// baseline (295.369 us; speedup 1.0000x reference)
//
#include <hip/hip_runtime.h>
#include <math.h>

#define SDF_W      7000.0f
#define EIK_W      600.0f
#define ORI_W      500.0f
#define NEAR_ORI_W 10.0f
#define GRADN_W    200.0f

#define NWAVE  8        // waves per 512-thread block
#define QW     16       // queries per wave in nn_scan (wave-uniform)
#define CHKI   32       // iterations per tracked chunk (CHKI*64 = 2048 points)
#define QPW    8        // queries per wave in recover_k

// ws layout (computed at launch):
//   fmt      : float4[SPfull]   formatted points {x,y,z,-|s|^2/2}, padded + prefetch pad
//   recs     : float4[QT]       per-query {M1, M2, id1, id2}, id = (chunk<<6)|lane
//   partials : float[5 * RB]    per-block loss partials

__device__ __forceinline__ float neg_half_norm2(float sx, float sy, float sz) {
    return -0.5f * fmaf(sx, sx, fmaf(sy, sy, sz * sz));
}
// Deterministic score; bit-identical between nn_scan and recover_k (both read fmt).
__device__ __forceinline__ float score(float qx, float qy, float qz,
                                       float sx, float sy, float sz, float nh) {
    return fmaf(qx, sx, fmaf(qy, sy, fmaf(qz, sz, nh)));
}

__device__ __forceinline__ float dot_fmt(const float4* __restrict__ fmt,
                                         const float* __restrict__ norms, int j,
                                         float qx, float qy, float qz) {
    float4 s = fmt[j];
    return fmaf(qx - s.x, norms[3*j],
           fmaf(qy - s.y, norms[3*j+1], (qz - s.z) * norms[3*j+2]));
}

// ---------------------------------------------------------------------------
// Pre-pass: format surface points as {x,y,z,-|s|^2/2}; pad with sentinels so
// the scan loop needs no bounds checks and can prefetch one group past the end.
// ---------------------------------------------------------------------------
__global__ __launch_bounds__(256) void fmt_k(
    const float* __restrict__ surf, float4* __restrict__ fmt, int S, int SPfull)
{
    int p = blockIdx.x * 256 + threadIdx.x;
    if (p >= SPfull) return;
    if (p < S) {
        float sx = surf[3*p], sy = surf[3*p+1], sz = surf[3*p+2];
        fmt[p] = make_float4(sx, sy, sz, neg_half_norm2(sx, sy, sz));
    } else {
        fmt[p] = make_float4(0.f, 0.f, 0.f, -3.0e38f);   // never wins
    }
}

// ---------------------------------------------------------------------------
// Hot kernel: queries wave-uniform (SGPR-resident), points lane-distributed.
// Lane l owns point column {i*64+l}: one coalesced global_load_dwordx4 per
// 64 points per wave — no LDS, no barriers. Per-lane top-2 per query with
// (chunk,lane) id; cross-lane shfl-tree merge at the end.
// waves_per_eu(4): min 4 waves/EU (no max pin) — round 6's (2,2) pin forced
// 2-deep occupancy and cost ~1.6x per-instruction issue efficiency.
// ---------------------------------------------------------------------------
__global__ __launch_bounds__(512) __attribute__((amdgpu_waves_per_eu(4)))
void nn_scan(const float* __restrict__ offq, const float* __restrict__ nearq,
             const float4* __restrict__ fmt, float4* __restrict__ recs,
             int nIter, int Qoff, int QT)
{
    const int lane = threadIdx.x & 63;
    const int wv   = __builtin_amdgcn_readfirstlane((int)threadIdx.x >> 6);
    const int qbase = (blockIdx.x * NWAVE + wv) * QW;

    // QW wave-uniform queries (same values in every lane)
    float qx[QW], qy[QW], qz[QW];
    #pragma unroll
    for (int j = 0; j < QW; ++j) {
        int q = qbase + j;
        float x = 0.f, y = 0.f, z = 0.f;
        if (q < QT) {
            const float* p = (q < Qoff) ? (offq + 3 * q) : (nearq + 3 * (q - Qoff));
            x = p[0]; y = p[1]; z = p[2];
        }
        qx[j] = x; qy[j] = y; qz[j] = z;
    }

    float M1[QW], M2[QW];
    int id1[QW], id2[QW];
    #pragma unroll
    for (int j = 0; j < QW; ++j) {
        M1[j] = -3.0e38f; M2[j] = -3.0e38f; id1[j] = 0; id2[j] = 0;
    }

    const int nCh = (nIter + CHKI - 1) / CHKI;
    const float4* fp = fmt + lane;
    float4 cur = fp[0];
    int i = 0;
    #pragma unroll 1
    for (int cc = 0; cc < nCh; ++cc) {
        float P1[QW], P2[QW];
        #pragma unroll
        for (int j = 0; j < QW; ++j) { P1[j] = M1[j]; P2[j] = M2[j]; }
        const int iEnd = min(nIter, (cc + 1) * CHKI);
        #pragma unroll 2
        for (; i < iEnd; ++i) {
            float4 nxt = fp[(i + 1) * 64];              // prefetch (pad-safe)
            #pragma unroll
            for (int j = 0; j < QW; ++j) {
                float g = score(qx[j], qy[j], qz[j], cur.x, cur.y, cur.z, cur.w);
                M2[j] = __builtin_amdgcn_fmed3f(g, M1[j], M2[j]);  // uses OLD M1
                M1[j] = fmaxf(M1[j], g);
            }
            cur = nxt;
        }
        const int cid = (cc << 6) | lane;
        #pragma unroll
        for (int j = 0; j < QW; ++j) {
            id1[j] = (M1[j] != P1[j]) ? cid : id1[j];
            id2[j] = (M2[j] != P2[j]) ? cid : id2[j];
        }
    }

    // ---- cross-lane top-2 merge per query (shfl_down tree; lane 0 result) ----
    #pragma unroll 1
    for (int j = 0; j < QW; ++j) {
        float m1 = M1[j], m2 = M2[j];
        int i1 = id1[j], i2 = id2[j];
        #pragma unroll
        for (int off = 32; off > 0; off >>= 1) {
            float b1 = __shfl_down(m1, off);
            float b2 = __shfl_down(m2, off);
            int   c1 = __shfl_down(i1, off);
            int   c2 = __shfl_down(i2, off);
            if (b1 > m1) {
                bool ka = (m1 > b2);
                m2 = ka ? m1 : b2;  i2 = ka ? i1 : c2;
                m1 = b1;            i1 = c1;
            } else {
                bool kb = (b1 > m2);
                m2 = kb ? b1 : m2;  i2 = kb ? c1 : i2;
            }
        }
        if (lane == 0 && qbase + j < QT)
            recs[qbase + j] = make_float4(m1, m2, __int_as_float(i1), __int_as_float(i2));
    }
}

// ---------------------------------------------------------------------------
// Recovery: per query, the M1 candidate set is 32 points {(cc1*CHKI+k)*64+ln1}
// and likewise for M2. One wave resolves BOTH with a single split ballot:
// lanes 0-31 test M1 candidates, lanes 32-63 test M2. Small losses fused.
// (No occupancy attribute — round 6's (4,4) pin was unnecessary.)
// ---------------------------------------------------------------------------
__global__ __launch_bounds__(512)
void recover_k(const float* __restrict__ offq, const float* __restrict__ nearq,
               const float4* __restrict__ fmt, const float* __restrict__ norms,
               const float* __restrict__ nmpred, const float* __restrict__ nppred,
               const float* __restrict__ mp, const float* __restrict__ mg,
               const float* __restrict__ sn,
               const float4* __restrict__ recs, float* __restrict__ partials,
               int S, int Qoff, int QT, int N, int RB)
{
    const int t    = threadIdx.x;
    const int lane = t & 63;
    const int wv   = t >> 6;
    const int q0   = (blockIdx.x * NWAVE + wv) * QPW;

    float accOri = 0.f, accNori = 0.f;               // lane 0 accumulates
    for (int u = 0; u < QPW; ++u) {
        int q = q0 + u;
        if (q >= QT) break;
        float4 r = recs[q];
        float M1 = r.x, M2 = r.y;
        int i1 = __float_as_int(r.z), i2 = __float_as_int(r.w);
        int cc1 = i1 >> 6, ln1 = i1 & 63;
        int cc2 = i2 >> 6, ln2 = i2 & 63;

        bool isNear = (q >= Qoff);
        const float* qp = isNear ? (nearq + 3 * (q - Qoff)) : (offq + 3 * q);
        float qx = qp[0], qy = qp[1], qz = qp[2];

        int half = lane >> 5;
        int k    = lane & 31;
        int p    = ((half ? cc2 : cc1) * CHKI + k) * 64 + (half ? ln2 : ln1);
        float target = half ? M2 : M1;
        float g = -3.0e38f, dotv = 0.f;
        if (p < S) {
            float4 s4 = fmt[p];
            g = score(qx, qy, qz, s4.x, s4.y, s4.z, s4.w);   // bit-identical operands
            float nx = norms[3*p], ny = norms[3*p+1], nz = norms[3*p+2];
            dotv = fmaf(qx - s4.x, nx, fmaf(qy - s4.y, ny, (qz - s4.z) * nz));
        }
        unsigned long long m = __ballot(g == target);
        unsigned int lo = (unsigned int)m;            // M1 matches (lanes 0-31)
        unsigned int hi = (unsigned int)(m >> 32);    // M2 matches (lanes 32-63)

        float d1, d2;
        int k1 = -1;
        if (lo) {
            k1 = __ffs(lo) - 1;
            d1 = __shfl(dotv, k1);
        } else {
            d1 = dot_fmt(fmt, norms, 0, qx, qy, qz);  // defensive fallback
        }
        // exclusion only matters if top-2 values AND candidate sets coincide
        if (M1 == M2 && i1 == i2 && k1 >= 0) hi &= ~(1u << k1);
        if (hi) {
            int k2 = __ffs(hi) - 1;
            d2 = __shfl(dotv, 32 + k2);
        } else {
            int I1 = (k1 >= 0) ? ((cc1 * CHKI + k1) * 64 + ln1) : 0;
            int I2 = (I1 == 0 && S > 1) ? 1 : 0;
            d2 = dot_fmt(fmt, norms, I2, qx, qy, qz);
        }

        float ms = d1 + d2;                            // sign(mean)==sign(sum)
        float sgn = (ms > 0.f) ? 1.f : ((ms < 0.f) ? -1.f : 0.f);
        float pred = isNear ? nppred[q - Qoff] : nmpred[q];
        float term = fmaxf(0.f, -pred * sgn);
        if (lane == 0) {
            if (isNear) accNori += term; else accOri += term;
        }
    }

    // fused prep (small losses), grid-stride over N
    float sdf = 0.f, eik = 0.f, gn = 0.f;
    for (int i = blockIdx.x * 512 + t; i < N; i += (int)gridDim.x * 512) {
        float p = mp[i];
        sdf += p * p;
        float gx = mg[3*i], gy = mg[3*i+1], gz = mg[3*i+2];
        float nrm = sqrtf(fmaf(gx, gx, fmaf(gy, gy, gz * gz)));
        float d = nrm - 1.0f;
        eik += d * d;
        float nx = sn[3*i], ny = sn[3*i+1], nz = sn[3*i+2];
        float dx = gx - nx, dy = gy - ny, dz = gz - nz;
        gn += fmaf(dx, dx, fmaf(dy, dy, dz * dz));
    }

    float v0 = accOri, v1 = accNori, v2 = sdf, v3 = eik, v4 = gn;
    #pragma unroll
    for (int off = 32; off > 0; off >>= 1) {
        v0 += __shfl_down(v0, off);
        v1 += __shfl_down(v1, off);
        v2 += __shfl_down(v2, off);
        v3 += __shfl_down(v3, off);
        v4 += __shfl_down(v4, off);
    }
    __shared__ float red[5][NWAVE];
    if (lane == 0) {
        red[0][wv] = v0; red[1][wv] = v1; red[2][wv] = v2;
        red[3][wv] = v3; red[4][wv] = v4;
    }
    __syncthreads();
    if (t == 0) {
        #pragma unroll
        for (int kk = 0; kk < 5; ++kk) {
            float s = 0.f;
            #pragma unroll
            for (int w = 0; w < NWAVE; ++w) s += red[kk][w];
            partials[kk * RB + blockIdx.x] = s;
        }
    }
}

// ---------------------------------------------------------------------------
__global__ __launch_bounds__(256) void final_k(
    const float* __restrict__ partials, float* __restrict__ out,
    int N, int RB, int Qoff, int Qnear)
{
    __shared__ float r[5][256];
    int t = threadIdx.x;
    float s[5] = {0.f, 0.f, 0.f, 0.f, 0.f};
    for (int i = t; i < RB; i += 256) {
        #pragma unroll
        for (int k = 0; k < 5; ++k) s[k] += partials[k * RB + i];
    }
    #pragma unroll
    for (int k = 0; k < 5; ++k) r[k][t] = s[k];
    __syncthreads();
    for (int off = 128; off > 0; off >>= 1) {
        if (t < off) {
            #pragma unroll
            for (int k = 0; k < 5; ++k) r[k][t] += r[k][t + off];
        }
        __syncthreads();
    }
    if (t == 0) {
        float orim  = r[0][0] / (float)Qoff;
        float norim = r[1][0] / (float)Qnear;
        float sdfm  = r[2][0] / (float)N;
        float eikm  = r[3][0] / (float)N;
        float gnm   = r[4][0] / (3.0f * (float)N);
        out[0] = SDF_W * sdfm + EIK_W * eikm + ORI_W * orim
               + NEAR_ORI_W * norim + GRADN_W * gnm;
        out[1] = sdfm;
        out[2] = eikm;
        out[3] = orim;
        out[4] = norim;
        out[5] = gnm;
    }
}

extern "C" void kernel_launch(void* const* d_in, const int* in_sizes, int n_in,
                              void* d_out, int out_size, void* d_ws, size_t ws_size,
                              hipStream_t stream)
{
    const float* mp    = (const float*)d_in[0];  // manifold_pred      [N,1]
    const float* mg    = (const float*)d_in[1];  // manifold_grad      [N,3]
    const float* nmp   = (const float*)d_in[2];  // nonmanifold_pred   [N,1]
    const float* npp   = (const float*)d_in[3];  // near_points_pred   [N,1]
    const float* sp    = (const float*)d_in[4];  // surface_points     [S,3]
    const float* sn    = (const float*)d_in[5];  // surface_normals    [S,3]
    const float* offp  = (const float*)d_in[6];  // off_surface_points [Q,3]
    const float* nearp = (const float*)d_in[7];  // near_points        [Q,3]
    float* out = (float*)d_out;

    const int N     = in_sizes[0];
    const int S     = in_sizes[4] / 3;
    const int Qoff  = in_sizes[2];
    const int Qnear = in_sizes[3];
    const int QT    = Qoff + Qnear;

    const int nIter  = (S + 63) / 64;            // 64-point groups
    const int SPfull = nIter * 64 + 64;          // + one prefetch pad group

    float4* fmt      = (float4*)d_ws;
    float4* recs     = fmt + SPfull;
    float*  partials = (float*)(recs + QT);

    const int RB         = (QT + NWAVE * QPW - 1) / (NWAVE * QPW);   // 512
    const int scanBlocks = (QT + NWAVE * QW - 1) / (NWAVE * QW);     // 256

    fmt_k<<<(SPfull + 255) / 256, 256, 0, stream>>>(sp, fmt, S, SPfull);
    nn_scan<<<scanBlocks, 512, 0, stream>>>(offp, nearp, fmt, recs, nIter, Qoff, QT);
    recover_k<<<RB, 512, 0, stream>>>(offp, nearp, fmt, sn, nmp, npp,
                                      mp, mg, sn, recs, partials,
                                      S, Qoff, QT, N, RB);
    final_k<<<1, 256, 0, stream>>>(partials, out, N, RB, Qoff, Qnear);
}

// Round 8
// 173.965 us; speedup vs baseline: 1.6979x; 1.6979x over previous
//
#include <hip/hip_runtime.h>
#include <math.h>

#define SDF_W      7000.0f
#define EIK_W      600.0f
#define ORI_W      500.0f
#define NEAR_ORI_W 10.0f
#define GRADN_W    200.0f

#define NWAVE  8        // waves per 512-thread block
#define QW     16       // queries per wave in nn_scan (wave-uniform)
#define CHKI   32       // iterations per tracked chunk (CHKI*64 = 2048 points)
#define NSPLIT 2        // S-range split: doubles grid to 512 blocks = 4 waves/SIMD
#define QPW    8        // queries per wave in recover_k

// ws layout (computed at launch):
//   fmt      : float4[SPfull]      formatted points {x,y,z,-|s|^2/2}, padded
//   recs     : float4[QT*NSPLIT]   per-(query,part) {M1, M2, id1, id2}, id=(gchunk<<6)|lane
//   partials : float[5 * RB]       per-block loss partials

__device__ __forceinline__ float neg_half_norm2(float sx, float sy, float sz) {
    return -0.5f * fmaf(sx, sx, fmaf(sy, sy, sz * sz));
}
// Deterministic score; bit-identical between nn_scan and recover_k (both read fmt).
__device__ __forceinline__ float score(float qx, float qy, float qz,
                                       float sx, float sy, float sz, float nh) {
    return fmaf(qx, sx, fmaf(qy, sy, fmaf(qz, sz, nh)));
}

__device__ __forceinline__ float dot_fmt(const float4* __restrict__ fmt,
                                         const float* __restrict__ norms, int j,
                                         float qx, float qy, float qz) {
    float4 s = fmt[j];
    return fmaf(qx - s.x, norms[3*j],
           fmaf(qy - s.y, norms[3*j+1], (qz - s.z) * norms[3*j+2]));
}

// ---------------------------------------------------------------------------
// Pre-pass: format surface points as {x,y,z,-|s|^2/2}; sentinel-padded so the
// scan loop needs no bounds checks and can prefetch one group past the end.
// ---------------------------------------------------------------------------
__global__ __launch_bounds__(256) void fmt_k(
    const float* __restrict__ surf, float4* __restrict__ fmt, int S, int SPfull)
{
    int p = blockIdx.x * 256 + threadIdx.x;
    if (p >= SPfull) return;
    if (p < S) {
        float sx = surf[3*p], sy = surf[3*p+1], sz = surf[3*p+2];
        fmt[p] = make_float4(sx, sy, sz, neg_half_norm2(sx, sy, sz));
    } else {
        fmt[p] = make_float4(0.f, 0.f, 0.f, -3.0e38f);   // never wins
    }
}

// ---------------------------------------------------------------------------
// Hot kernel: queries wave-uniform, points lane-distributed (no LDS, no
// barriers; one coalesced dwordx4 per 64 points per wave). NSPLIT=2 splits
// the S-range so the grid is 512 blocks = 2 blocks/CU = 4 waves/SIMD —
// round 6 was grid-limited to 2 waves/SIMD (256 blocks), not attribute-
// limited. waves_per_eu(2,4): min 2 keeps the VGPR budget at 256 (the r6
// codegen that fit in 88 VGPR with ZERO spill); r7's min=4 squeezed the
// budget under the live state and produced 200 MB/dispatch of spill traffic.
// ---------------------------------------------------------------------------
__global__ __launch_bounds__(512) __attribute__((amdgpu_waves_per_eu(2, 4)))
void nn_scan(const float* __restrict__ offq, const float* __restrict__ nearq,
             const float4* __restrict__ fmt, float4* __restrict__ recs,
             int nIter, int iPart, int Qoff, int QT)
{
    const int lane = threadIdx.x & 63;
    const int wv   = __builtin_amdgcn_readfirstlane((int)threadIdx.x >> 6);
    const int part = blockIdx.x & (NSPLIT - 1);
    const int qbase = ((blockIdx.x >> 1) * NWAVE + wv) * QW;

    // this part's iteration range (iPart is a multiple of CHKI)
    int iBeg = part * iPart;        if (iBeg > nIter) iBeg = nIter;
    int iEndAll = iBeg + iPart;     if (iEndAll > nIter) iEndAll = nIter;
    const int chunkBase = iBeg / CHKI;

    // QW wave-uniform queries (same values in every lane)
    float qx[QW], qy[QW], qz[QW];
    #pragma unroll
    for (int j = 0; j < QW; ++j) {
        int q = qbase + j;
        float x = 0.f, y = 0.f, z = 0.f;
        if (q < QT) {
            const float* p = (q < Qoff) ? (offq + 3 * q) : (nearq + 3 * (q - Qoff));
            x = p[0]; y = p[1]; z = p[2];
        }
        qx[j] = x; qy[j] = y; qz[j] = z;
    }

    float M1[QW], M2[QW];
    int id1[QW], id2[QW];
    #pragma unroll
    for (int j = 0; j < QW; ++j) {
        M1[j] = -3.0e38f; M2[j] = -3.0e38f; id1[j] = 0; id2[j] = 0;
    }

    const int nCh = (iEndAll - iBeg + CHKI - 1) / CHKI;
    const float4* fp = fmt + lane;
    float4 cur = fp[iBeg * 64];
    int i = iBeg;
    #pragma unroll 1
    for (int cc = 0; cc < nCh; ++cc) {
        float P1[QW], P2[QW];
        #pragma unroll
        for (int j = 0; j < QW; ++j) { P1[j] = M1[j]; P2[j] = M2[j]; }
        const int iEnd = min(iEndAll, iBeg + (cc + 1) * CHKI);
        #pragma unroll 2
        for (; i < iEnd; ++i) {
            float4 nxt = fp[(i + 1) * 64];              // prefetch (pad-safe)
            #pragma unroll
            for (int j = 0; j < QW; ++j) {
                float g = score(qx[j], qy[j], qz[j], cur.x, cur.y, cur.z, cur.w);
                M2[j] = __builtin_amdgcn_fmed3f(g, M1[j], M2[j]);  // uses OLD M1
                M1[j] = fmaxf(M1[j], g);
            }
            cur = nxt;
        }
        const int cid = ((chunkBase + cc) << 6) | lane;  // GLOBAL chunk id
        #pragma unroll
        for (int j = 0; j < QW; ++j) {
            id1[j] = (M1[j] != P1[j]) ? cid : id1[j];
            id2[j] = (M2[j] != P2[j]) ? cid : id2[j];
        }
    }

    // ---- cross-lane top-2 merge per query (shfl_down tree; lane 0 result) ----
    #pragma unroll 1
    for (int j = 0; j < QW; ++j) {
        float m1 = M1[j], m2 = M2[j];
        int i1 = id1[j], i2 = id2[j];
        #pragma unroll
        for (int off = 32; off > 0; off >>= 1) {
            float b1 = __shfl_down(m1, off);
            float b2 = __shfl_down(m2, off);
            int   c1 = __shfl_down(i1, off);
            int   c2 = __shfl_down(i2, off);
            if (b1 > m1) {
                bool ka = (m1 > b2);
                m2 = ka ? m1 : b2;  i2 = ka ? i1 : c2;
                m1 = b1;            i1 = c1;
            } else {
                bool kb = (b1 > m2);
                m2 = kb ? b1 : m2;  i2 = kb ? c1 : i2;
            }
        }
        if (lane == 0 && qbase + j < QT)
            recs[(qbase + j) * NSPLIT + part] =
                make_float4(m1, m2, __int_as_float(i1), __int_as_float(i2));
    }
}

// ---------------------------------------------------------------------------
// Recovery: merge the NSPLIT part-records, then resolve both tracked
// candidate sets (32 stride-64 points each) with one split ballot:
// lanes 0-31 test M1, lanes 32-63 test M2. Small losses fused (grid-stride).
// waves_per_eu(2,2): 256-reg budget — bare launch_bounds gave VGPR=16 +
// massive scratch spills in round 3 (the persistent ~80 us tail suspect).
// ---------------------------------------------------------------------------
__global__ __launch_bounds__(512) __attribute__((amdgpu_waves_per_eu(2, 2)))
void recover_k(const float* __restrict__ offq, const float* __restrict__ nearq,
               const float4* __restrict__ fmt, const float* __restrict__ norms,
               const float* __restrict__ nmpred, const float* __restrict__ nppred,
               const float* __restrict__ mp, const float* __restrict__ mg,
               const float* __restrict__ sn,
               const float4* __restrict__ recs, float* __restrict__ partials,
               int S, int Qoff, int QT, int N, int RB)
{
    const int t    = threadIdx.x;
    const int lane = t & 63;
    const int wv   = t >> 6;
    const int q0   = (blockIdx.x * NWAVE + wv) * QPW;

    float accOri = 0.f, accNori = 0.f;               // lane 0 accumulates
    for (int u = 0; u < QPW; ++u) {
        int q = q0 + u;
        if (q >= QT) break;

        // merge the NSPLIT part-records into global top-2
        float M1 = -3.0e38f, M2 = -3.0e38f;
        int i1 = 0, i2 = 0;
        #pragma unroll
        for (int h = 0; h < NSPLIT; ++h) {
            float4 r = recs[q * NSPLIT + h];
            float a1 = r.x, a2 = r.y;
            int ac1 = __float_as_int(r.z), ac2 = __float_as_int(r.w);
            if (a1 > M1)      { M2 = M1; i2 = i1; M1 = a1; i1 = ac1; }
            else if (a1 > M2) { M2 = a1; i2 = ac1; }
            if (a2 > M2)      { M2 = a2; i2 = ac2; }
        }
        int cc1 = i1 >> 6, ln1 = i1 & 63;
        int cc2 = i2 >> 6, ln2 = i2 & 63;

        bool isNear = (q >= Qoff);
        const float* qp = isNear ? (nearq + 3 * (q - Qoff)) : (offq + 3 * q);
        float qx = qp[0], qy = qp[1], qz = qp[2];

        int half = lane >> 5;
        int k    = lane & 31;
        int p    = ((half ? cc2 : cc1) * CHKI + k) * 64 + (half ? ln2 : ln1);
        float target = half ? M2 : M1;
        float g = -3.0e38f, dotv = 0.f;
        if (p < S) {
            float4 s4 = fmt[p];
            g = score(qx, qy, qz, s4.x, s4.y, s4.z, s4.w);   // bit-identical operands
            float nx = norms[3*p], ny = norms[3*p+1], nz = norms[3*p+2];
            dotv = fmaf(qx - s4.x, nx, fmaf(qy - s4.y, ny, (qz - s4.z) * nz));
        }
        unsigned long long m = __ballot(g == target);
        unsigned int lo = (unsigned int)m;            // M1 matches (lanes 0-31)
        unsigned int hi = (unsigned int)(m >> 32);    // M2 matches (lanes 32-63)

        float d1, d2;
        int k1 = -1;
        if (lo) {
            k1 = __ffs(lo) - 1;
            d1 = __shfl(dotv, k1);
        } else {
            d1 = dot_fmt(fmt, norms, 0, qx, qy, qz);  // defensive fallback
        }
        // exclusion only matters if top-2 values AND candidate sets coincide
        if (M1 == M2 && i1 == i2 && k1 >= 0) hi &= ~(1u << k1);
        if (hi) {
            int k2 = __ffs(hi) - 1;
            d2 = __shfl(dotv, 32 + k2);
        } else {
            int I1 = (k1 >= 0) ? ((cc1 * CHKI + k1) * 64 + ln1) : 0;
            int I2 = (I1 == 0 && S > 1) ? 1 : 0;
            d2 = dot_fmt(fmt, norms, I2, qx, qy, qz);
        }

        float ms = d1 + d2;                            // sign(mean)==sign(sum)
        float sgn = (ms > 0.f) ? 1.f : ((ms < 0.f) ? -1.f : 0.f);
        float pred = isNear ? nppred[q - Qoff] : nmpred[q];
        float term = fmaxf(0.f, -pred * sgn);
        if (lane == 0) {
            if (isNear) accNori += term; else accOri += term;
        }
    }

    // fused prep (small losses), grid-stride over N
    float sdf = 0.f, eik = 0.f, gn = 0.f;
    for (int i = blockIdx.x * 512 + t; i < N; i += (int)gridDim.x * 512) {
        float p = mp[i];
        sdf += p * p;
        float gx = mg[3*i], gy = mg[3*i+1], gz = mg[3*i+2];
        float nrm = sqrtf(fmaf(gx, gx, fmaf(gy, gy, gz * gz)));
        float d = nrm - 1.0f;
        eik += d * d;
        float nx = sn[3*i], ny = sn[3*i+1], nz = sn[3*i+2];
        float dx = gx - nx, dy = gy - ny, dz = gz - nz;
        gn += fmaf(dx, dx, fmaf(dy, dy, dz * dz));
    }

    float v0 = accOri, v1 = accNori, v2 = sdf, v3 = eik, v4 = gn;
    #pragma unroll
    for (int off = 32; off > 0; off >>= 1) {
        v0 += __shfl_down(v0, off);
        v1 += __shfl_down(v1, off);
        v2 += __shfl_down(v2, off);
        v3 += __shfl_down(v3, off);
        v4 += __shfl_down(v4, off);
    }
    __shared__ float red[5][NWAVE];
    if (lane == 0) {
        red[0][wv] = v0; red[1][wv] = v1; red[2][wv] = v2;
        red[3][wv] = v3; red[4][wv] = v4;
    }
    __syncthreads();
    if (t == 0) {
        #pragma unroll
        for (int kk = 0; kk < 5; ++kk) {
            float s = 0.f;
            #pragma unroll
            for (int w = 0; w < NWAVE; ++w) s += red[kk][w];
            partials[kk * RB + blockIdx.x] = s;
        }
    }
}

// ---------------------------------------------------------------------------
__global__ __launch_bounds__(256) void final_k(
    const float* __restrict__ partials, float* __restrict__ out,
    int N, int RB, int Qoff, int Qnear)
{
    __shared__ float r[5][256];
    int t = threadIdx.x;
    float s[5] = {0.f, 0.f, 0.f, 0.f, 0.f};
    for (int i = t; i < RB; i += 256) {
        #pragma unroll
        for (int k = 0; k < 5; ++k) s[k] += partials[k * RB + i];
    }
    #pragma unroll
    for (int k = 0; k < 5; ++k) r[k][t] = s[k];
    __syncthreads();
    for (int off = 128; off > 0; off >>= 1) {
        if (t < off) {
            #pragma unroll
            for (int k = 0; k < 5; ++k) r[k][t] += r[k][t + off];
        }
        __syncthreads();
    }
    if (t == 0) {
        float orim  = r[0][0] / (float)Qoff;
        float norim = r[1][0] / (float)Qnear;
        float sdfm  = r[2][0] / (float)N;
        float eikm  = r[3][0] / (float)N;
        float gnm   = r[4][0] / (3.0f * (float)N);
        out[0] = SDF_W * sdfm + EIK_W * eikm + ORI_W * orim
               + NEAR_ORI_W * norim + GRADN_W * gnm;
        out[1] = sdfm;
        out[2] = eikm;
        out[3] = orim;
        out[4] = norim;
        out[5] = gnm;
    }
}

extern "C" void kernel_launch(void* const* d_in, const int* in_sizes, int n_in,
                              void* d_out, int out_size, void* d_ws, size_t ws_size,
                              hipStream_t stream)
{
    const float* mp    = (const float*)d_in[0];  // manifold_pred      [N,1]
    const float* mg    = (const float*)d_in[1];  // manifold_grad      [N,3]
    const float* nmp   = (const float*)d_in[2];  // nonmanifold_pred   [N,1]
    const float* npp   = (const float*)d_in[3];  // near_points_pred   [N,1]
    const float* sp    = (const float*)d_in[4];  // surface_points     [S,3]
    const float* sn    = (const float*)d_in[5];  // surface_normals    [S,3]
    const float* offp  = (const float*)d_in[6];  // off_surface_points [Q,3]
    const float* nearp = (const float*)d_in[7];  // near_points        [Q,3]
    float* out = (float*)d_out;

    const int N     = in_sizes[0];
    const int S     = in_sizes[4] / 3;
    const int Qoff  = in_sizes[2];
    const int Qnear = in_sizes[3];
    const int QT    = Qoff + Qnear;

    const int nIter  = (S + 63) / 64;            // 64-point groups
    const int SPfull = nIter * 64 + 64;          // + one prefetch pad group
    // per-part iteration count, CHKI-aligned
    const int iPart  = (((nIter + NSPLIT - 1) / NSPLIT) + CHKI - 1) & ~(CHKI - 1);

    float4* fmt      = (float4*)d_ws;
    float4* recs     = fmt + SPfull;
    float*  partials = (float*)(recs + (size_t)QT * NSPLIT);

    const int RB         = (QT + NWAVE * QPW - 1) / (NWAVE * QPW);          // 512
    const int scanBlocks = ((QT + NWAVE * QW - 1) / (NWAVE * QW)) * NSPLIT; // 512

    fmt_k<<<(SPfull + 255) / 256, 256, 0, stream>>>(sp, fmt, S, SPfull);
    nn_scan<<<scanBlocks, 512, 0, stream>>>(offp, nearp, fmt, recs,
                                            nIter, iPart, Qoff, QT);
    recover_k<<<RB, 512, 0, stream>>>(offp, nearp, fmt, sn, nmp, npp,
                                      mp, mg, sn, recs, partials,
                                      S, Qoff, QT, N, RB);
    final_k<<<1, 256, 0, stream>>>(partials, out, N, RB, Qoff, Qnear);
}